// Round 4
// baseline (29.758 us; speedup 1.0000x reference)
//
#include <hip/hip_runtime.h>
#include <stdint.h>
#include <math.h>

#define NB 8
#define NN 128
#define NC 64
#define DEG 10
#define HP (DEG / 2)
#define NUM_STEPS 5

// ---------------------------------------------------------------------------
// Kernel 1: neighbor-list extraction (distinct neighbors sorted ascending,
// matching to_dense_adj -> top_k tie/order semantics). Bitmask + ctz walk.
// ---------------------------------------------------------------------------
__global__ __launch_bounds__(256) void build_nbrs(
    const int* __restrict__ dst_s, const int* __restrict__ dst_t,
    int* __restrict__ nbr_s, int* __restrict__ deg_s,
    int* __restrict__ nbr_t, int* __restrict__ deg_t)
{
    int g = blockIdx.x * 256 + threadIdx.x;   // grid is exactly 2*NB*NN threads
    const int* dst; int* nbr; int* deg; int node;
    if (g < NB * NN) { node = g;           dst = dst_s; nbr = nbr_s; deg = deg_s; }
    else             { node = g - NB * NN; dst = dst_t; nbr = nbr_t; deg = deg_t; }

    unsigned long long mlo = 0ull, mhi = 0ull;
    #pragma unroll
    for (int k = 0; k < DEG; ++k) {
        int d = dst[node * DEG + k] & (NN - 1);
        if (d < 64) mlo |= 1ull << d;
        else        mhi |= 1ull << (d - 64);
    }
    int cnt = 0;
    while (mlo) { int t = __builtin_ctzll(mlo); mlo &= (mlo - 1ull); nbr[node * DEG + cnt] = t;      ++cnt; }
    while (mhi) { int t = __builtin_ctzll(mhi); mhi &= (mhi - 1ull); nbr[node * DEG + cnt] = 64 + t; ++cnt; }
    deg[node] = cnt;
    for (int p = cnt; p < DEG; ++p) nbr[node * DEG + p] = 0;  // masked slots, never used
}

// ---------------------------------------------------------------------------
// Kernel 2: sim[b,i,j] = dot(x_s[b,i,:], x_t[b,j,:]).  Block = (b,i), thread=j.
// ---------------------------------------------------------------------------
__global__ __launch_bounds__(128) void sim_kernel(
    const float* __restrict__ xs, const float* __restrict__ xt,
    float* __restrict__ sim)
{
    int bi = blockIdx.x;
    int b = bi >> 7, i = bi & 127, j = threadIdx.x;
    const float4* a  = (const float4*)(xs + (size_t)(b * NN + i) * NC);
    const float4* bt = (const float4*)(xt + (size_t)(b * NN + j) * NC);
    float acc = 0.f;
    #pragma unroll
    for (int k = 0; k < NC / 4; ++k) {
        float4 av = a[k], bv = bt[k];
        acc += av.x * bv.x + av.y * bv.y + av.z * bv.z + av.w * bv.w;
    }
    sim[(size_t)(b * NN + i) * NN + j] = acc;
}

// ---------------------------------------------------------------------------
// Kernel 3: per (b,i) block of 256 threads; TWO threads per pair (i,j):
//   j = tid>>1, h = tid&1; thread h owns rows p = h*5 .. h*5+4 of the 10x10.
// Rank-factored Sinkhorn: S[p][q] == T[p][q]*a[p]*b[q] throughout, with
// T = exp(S_hat) staged once per block (exp monotone + row-softmax
// normalizes => max-subtraction unnecessary; |sim| <~ 45 keeps all
// products finite). Column sums are split p-wise across the thread pair and
// combined with one shfl_xor(1) (partners are adjacent lanes, same wave);
// fp add is commutative so both halves compute identical c. b-updates are
// duplicated (identical inputs -> identical values). Row phase is fully
// thread-local. argmax_q S[p][q] == argmax_q T[p][q]*b[q] (a[p]>0 const/row).
// Masked entries stay EXACT zeros (predicated), matching the reference.
// ---------------------------------------------------------------------------
__global__ __launch_bounds__(256, 4) void main_kernel(
    const float* __restrict__ sim,
    const int* __restrict__ nbr_s, const int* __restrict__ deg_s,
    const int* __restrict__ nbr_t, const int* __restrict__ deg_t,
    float* __restrict__ out)
{
    __shared__ float srow[DEG][NN];   // raw sim rows of i's neighbors (cost gather)
    __shared__ float erow[DEG][NN];   // exp(sim) rows (T gather)
    __shared__ float smax[4], ssum[4];

    int bi = blockIdx.x;
    int b = bi >> 7, i = bi & 127;
    int tid = threadIdx.x;
    int j = tid >> 1;                 // pair id 0..127
    int h = tid & 1;                  // which half of the rows this thread owns
    int gs = b * NN + i, gt = b * NN + j;

    int dsi = deg_s[gs];              // uniform across block

    // stage neighbor sim rows + exp: half-block (tid>>7) picks the row,
    // (tid&127) the column -> two full coalesced rows per pass.
    {
        int col = tid & 127, rh = tid >> 7;
        #pragma unroll
        for (int pb = 0; pb < DEG; pb += 2) {
            int row = pb + rh;
            if (row < dsi) {
                float s = sim[(size_t)(b * NN + nbr_s[gs * DEG + row]) * NN + col];
                srow[row][col] = s;
                erow[row][col] = __expf(s);
            }
        }
    }
    float simv = sim[(size_t)gs * NN + j];   // prefetch for epilogue (dup per pair)
    __syncthreads();

    int dtj = deg_t[gt];
    int ntq[DEG];
    #pragma unroll
    for (int q = 0; q < DEG; ++q) ntq[q] = nbr_t[gt * DEG + q];

    // Gather own half of T = exp(S_hat); a = (1/rowsum)/tau; b = valid?1:0
    float T[HP][DEG];
    float a[HP], bv[DEG];
    #pragma unroll
    for (int q = 0; q < DEG; ++q) bv[q] = (q < dtj) ? 1.0f : 0.0f;

    #pragma unroll
    for (int pp = 0; pp < HP; ++pp) {
        int p = h * HP + pp;
        bool pv = (p < dsi);
        float sum = 0.f;
        #pragma unroll
        for (int q = 0; q < DEG; ++q) {
            bool ok = pv && (q < dtj);
            float e = ok ? erow[p][ntq[q]] : 0.0f;
            T[pp][q] = e;
            sum += e;
        }
        a[pp] = pv ? __builtin_amdgcn_rcpf(sum) * 10.0f : 0.0f;
    }

    // 5 Sinkhorn iterations on the scale vectors only
    #pragma unroll 1
    for (int it = 0; it < NUM_STEPS; ++it) {
        // column phase: partial col-sums over own 5 rows, combine via shfl
        float part[DEG];
        #pragma unroll
        for (int q = 0; q < DEG; ++q) {
            float c = T[0][q] * a[0];
            #pragma unroll
            for (int pp = 1; pp < HP; ++pp) c = fmaf(T[pp][q], a[pp], c);
            part[q] = c;
        }
        #pragma unroll
        for (int q = 0; q < DEG; ++q) {
            float c = part[q] + __shfl_xor(part[q], 1);   // commutative: same on both
            float bq = bv[q];
            bv[q] = (q < dtj) ? bq * __builtin_amdgcn_rcpf(fmaf(bq, c, 1e-8f)) : 0.0f;
        }
        // row phase: fully local to own rows
        #pragma unroll
        for (int pp = 0; pp < HP; ++pp) {
            float r = T[pp][0] * bv[0];
            #pragma unroll
            for (int q = 1; q < DEG; ++q) r = fmaf(T[pp][q], bv[q], r);
            float ap = a[pp];
            int p = h * HP + pp;
            a[pp] = (p < dsi) ? ap * __builtin_amdgcn_rcpf(fmaf(ap, r, 1e-8f)) : 0.0f;
        }
    }

    // argmax per own row over T[pp][q]*b[q] (first max), cost gather from LDS
    float cpart = 0.f;
    #pragma unroll
    for (int pp = 0; pp < HP; ++pp) {
        int p = h * HP + pp;
        if (p < dsi) {                       // per-lane predicated
            float best = T[pp][0] * bv[0];
            int   bc   = ntq[0];
            #pragma unroll
            for (int q = 1; q < DEG; ++q) {
                float vq = T[pp][q] * bv[q];
                if (vq > best) { best = vq; bc = ntq[q]; }
            }
            cpart += srow[p][bc];
        }
    }
    float cost = cpart + __shfl_xor(cpart, 1);   // commutative: same on both

    float M = (float)((dsi > dtj) ? dsi : dtj);
    float v = simv + cost / (1.0f + M);

    // block softmax over j: every pair's v appears twice in the 256 threads,
    // so block sum = 2 * true sum -> multiply by 0.5 (exact).
    float wm = v;
    #pragma unroll
    for (int off = 32; off; off >>= 1) wm = fmaxf(wm, __shfl_xor(wm, off));
    int wid = tid >> 6;
    if ((tid & 63) == 0) smax[wid] = wm;
    __syncthreads();
    float bm = fmaxf(fmaxf(smax[0], smax[1]), fmaxf(smax[2], smax[3]));
    float e = __expf(v - bm);
    float wsum = e;
    #pragma unroll
    for (int off = 32; off; off >>= 1) wsum += __shfl_xor(wsum, off);
    if ((tid & 63) == 0) ssum[wid] = wsum;
    __syncthreads();
    float bs = (ssum[0] + ssum[1] + ssum[2] + ssum[3]) * 0.5f;

    if (h == 0) out[(size_t)gs * NN + j] = e / bs;
}

// ---------------------------------------------------------------------------
extern "C" void kernel_launch(void* const* d_in, const int* in_sizes, int n_in,
                              void* d_out, int out_size, void* d_ws, size_t ws_size,
                              hipStream_t stream) {
    (void)in_sizes; (void)n_in; (void)out_size; (void)ws_size;
    const float* x_s  = (const float*)d_in[0];
    const int*   ei_s = (const int*)  d_in[1];
    const float* x_t  = (const float*)d_in[3];
    const int*   ei_t = (const int*)  d_in[4];
    float* out = (float*)d_out;

    char* ws = (char*)d_ws;
    float* sim   = (float*)ws;                          // 8*128*128*4 = 524288 B
    int*   nbr_s = (int*)(ws + 524288);                 // 1024*10*4   = 40960 B
    int*   deg_s = (int*)(ws + 524288 + 40960);         // 1024*4      = 4096 B
    int*   nbr_t = (int*)(ws + 524288 + 45056);         // 40960 B
    int*   deg_t = (int*)(ws + 524288 + 86016);         // 4096 B

    const int* dst_s = ei_s + NB * NN * DEG;            // second row of edge_index
    const int* dst_t = ei_t + NB * NN * DEG;

    hipLaunchKernelGGL(build_nbrs, dim3(8), dim3(256), 0, stream,
                       dst_s, dst_t, nbr_s, deg_s, nbr_t, deg_t);
    hipLaunchKernelGGL(sim_kernel, dim3(NB * NN), dim3(NN), 0, stream,
                       x_s, x_t, sim);
    hipLaunchKernelGGL(main_kernel, dim3(NB * NN), dim3(256), 0, stream,
                       sim, nbr_s, deg_s, nbr_t, deg_t, out);
}

// Round 5
// 27.546 us; speedup vs baseline: 1.0803x; 1.0803x over previous
//
#include <hip/hip_runtime.h>
#include <stdint.h>
#include <math.h>

#define NB 8
#define NN 128
#define NC 64
#define DEG 10
#define HP (DEG / 2)
#define NUM_STEPS 5

// ---------------------------------------------------------------------------
// Single fused kernel. Block = (b,i) with 256 threads.
//   sim phase:   c = tid&127 (column), half = tid>>7. Stage <=11 x_s rows in
//                LDS; each thread keeps its x_t row in 16 float4 regs; dots
//                use the exact sim_kernel expression tree.
//   sinkhorn:    j = tid>>1, h = tid&1 (two threads per (i,j) pair; thread h
//                owns rows h*5..h*5+4 of the 10x10). Rank-factored Sinkhorn:
//                S[p][q] == T[p][q]*a[p]*b[q] with T = exp(S_hat) (exp is
//                monotone + row-softmax normalizes => max-subtraction
//                unnecessary; |sim| <~ 45 keeps products finite).
//   neighbor extraction is inline: bitmask + STATIC 10-slot ctz walk (no
//   runtime-indexed private arrays -> no scratch), ascending distinct order
//   == to_dense_adj->top_k semantics.
// Masked entries stay EXACT zeros (predicated), matching the reference.
// ---------------------------------------------------------------------------
__global__ __launch_bounds__(256, 3) void fused_kernel(
    const float* __restrict__ xs, const float* __restrict__ xt,
    const int* __restrict__ dst_s, const int* __restrict__ dst_t,
    float* __restrict__ out)
{
    __shared__ float  srow[DEG + 1][NN];   // slots 0..9: neighbor sim rows; 10: self row
    __shared__ float  erow[DEG][NN];       // exp(sim) rows
    __shared__ float4 xsl[DEG + 1][NC / 4];
    __shared__ float  smax[4], ssum[4];

    const int bi  = blockIdx.x;
    const int b   = bi >> 7, i = bi & 127;
    const int tid = threadIdx.x;
    const int c   = tid & 127;             // sim column
    const int half = tid >> 7;
    const int gs  = b * NN + i;

    // ---- s-side neighbor mask (wave-uniform scalar loads) ----
    unsigned long long slo = 0ull, shi = 0ull;
    #pragma unroll
    for (int k = 0; k < DEG; ++k) {
        int d = dst_s[gs * DEG + k] & (NN - 1);
        if (d < 64) slo |= 1ull << d; else shi |= 1ull << (d - 64);
    }
    const int dsi = __popcll(slo) + __popcll(shi);

    // ---- issue own x_t row load early (16 float4, lives through sim phase) ----
    const float4* xtr = (const float4*)(xt + (size_t)(b * NN + c) * NC);
    float4 xv[NC / 4];
    #pragma unroll
    for (int k = 0; k < NC / 4; ++k) xv[k] = xtr[k];

    // ---- stage x_s rows into LDS: threads 0..175, row = tid>>4, k = tid&15 ----
    if (tid < (DEG + 1) * 16) {
        int r = tid >> 4, k = tid & 15;
        int node = i;                       // r==10 -> self row
        if (r < DEG) {
            // select r-th set bit: static walk, scalar select (no arrays)
            unsigned long long lo = slo, hi = shi; int sel = 0;
            #pragma unroll
            for (int q = 0; q < DEG; ++q) {
                int t;
                if (lo)      { t = __builtin_ctzll(lo);      lo &= lo - 1ull; }
                else if (hi) { t = 64 + __builtin_ctzll(hi); hi &= hi - 1ull; }
                else t = 0;
                if (q == r) sel = t;
            }
            node = sel;
        }
        if (r == DEG || r < dsi)
            xsl[r][k] = ((const float4*)(xs + (size_t)(b * NN + node) * NC))[k];
    }
    __syncthreads();

    // ---- sim dots: half 0 -> slots 0..4 and self(10); half 1 -> slots 5..9 ----
    #pragma unroll
    for (int rr = 0; rr < HP + 1; ++rr) {
        int  r   = (rr == HP) ? DEG : (half * HP + rr);
        bool run = (rr == HP) ? (half == 0) : (r < dsi);   // wave-uniform
        if (run) {
            float acc = 0.f;
            #pragma unroll
            for (int k = 0; k < NC / 4; ++k) {
                float4 a4 = xsl[r][k];                     // LDS broadcast
                acc += a4.x * xv[k].x + a4.y * xv[k].y + a4.z * xv[k].z + a4.w * xv[k].w;
            }
            srow[r][c] = acc;
            if (r < DEG) erow[r][c] = __expf(acc);
        }
    }

    // ---- t-side neighbor list for pair j = tid>>1 (overlaps before sync) ----
    const int j = tid >> 1, h = tid & 1;
    const int gt = b * NN + j;
    unsigned long long tlo = 0ull, thi = 0ull;
    #pragma unroll
    for (int k = 0; k < DEG; ++k) {
        int d = dst_t[gt * DEG + k] & (NN - 1);
        if (d < 64) tlo |= 1ull << d; else thi |= 1ull << (d - 64);
    }
    const int dtj = __popcll(tlo) + __popcll(thi);
    int ntq[DEG];
    {
        unsigned long long lo = tlo, hi = thi;
        #pragma unroll
        for (int q = 0; q < DEG; ++q) {                    // static-indexed writes
            int t;
            if (lo)      { t = __builtin_ctzll(lo);      lo &= lo - 1ull; }
            else if (hi) { t = 64 + __builtin_ctzll(hi); hi &= hi - 1ull; }
            else t = 0;
            ntq[q] = t;
        }
    }
    __syncthreads();

    // ---- gather own half of T = exp(S_hat); a = (1/rowsum)/tau; b = valid?1:0
    float T[HP][DEG];
    float a[HP], bvv[DEG];
    #pragma unroll
    for (int q = 0; q < DEG; ++q) bvv[q] = (q < dtj) ? 1.0f : 0.0f;

    #pragma unroll
    for (int pp = 0; pp < HP; ++pp) {
        int p = h * HP + pp;
        bool pv = (p < dsi);
        float sum = 0.f;
        #pragma unroll
        for (int q = 0; q < DEG; ++q) {
            bool ok = pv && (q < dtj);
            float e = ok ? erow[p][ntq[q]] : 0.0f;
            T[pp][q] = e;
            sum += e;
        }
        a[pp] = pv ? __builtin_amdgcn_rcpf(sum) * 10.0f : 0.0f;
    }

    // ---- 5 Sinkhorn iterations on the scale vectors only ----
    #pragma unroll 1
    for (int it = 0; it < NUM_STEPS; ++it) {
        // column phase: partial col-sums over own 5 rows, combine via shfl
        float part[DEG];
        #pragma unroll
        for (int q = 0; q < DEG; ++q) {
            float cc = T[0][q] * a[0];
            #pragma unroll
            for (int pp = 1; pp < HP; ++pp) cc = fmaf(T[pp][q], a[pp], cc);
            part[q] = cc;
        }
        #pragma unroll
        for (int q = 0; q < DEG; ++q) {
            float cc = part[q] + __shfl_xor(part[q], 1);   // commutative: same both
            float bq = bvv[q];
            bvv[q] = (q < dtj) ? bq * __builtin_amdgcn_rcpf(fmaf(bq, cc, 1e-8f)) : 0.0f;
        }
        // row phase: fully local to own rows
        #pragma unroll
        for (int pp = 0; pp < HP; ++pp) {
            float r = T[pp][0] * bvv[0];
            #pragma unroll
            for (int q = 1; q < DEG; ++q) r = fmaf(T[pp][q], bvv[q], r);
            float ap = a[pp];
            int p = h * HP + pp;
            a[pp] = (p < dsi) ? ap * __builtin_amdgcn_rcpf(fmaf(ap, r, 1e-8f)) : 0.0f;
        }
    }

    // ---- argmax per own row over T[pp][q]*b[q] (first max), cost gather ----
    float cpart = 0.f;
    #pragma unroll
    for (int pp = 0; pp < HP; ++pp) {
        int p = h * HP + pp;
        if (p < dsi) {
            float best = T[pp][0] * bvv[0];
            int   bc   = ntq[0];
            #pragma unroll
            for (int q = 1; q < DEG; ++q) {
                float vq = T[pp][q] * bvv[q];
                if (vq > best) { best = vq; bc = ntq[q]; }
            }
            cpart += srow[p][bc];
        }
    }
    float cost = cpart + __shfl_xor(cpart, 1);             // commutative: same both

    float M = (float)((dsi > dtj) ? dsi : dtj);
    float simv = srow[DEG][j];
    float v = simv + cost / (1.0f + M);

    // ---- block softmax over j: each pair's v appears twice -> sum * 0.5 ----
    float wm = v;
    #pragma unroll
    for (int off = 32; off; off >>= 1) wm = fmaxf(wm, __shfl_xor(wm, off));
    int wid = tid >> 6;
    if ((tid & 63) == 0) smax[wid] = wm;
    __syncthreads();
    float bm = fmaxf(fmaxf(smax[0], smax[1]), fmaxf(smax[2], smax[3]));
    float e = __expf(v - bm);
    float wsum = e;
    #pragma unroll
    for (int off = 32; off; off >>= 1) wsum += __shfl_xor(wsum, off);
    if ((tid & 63) == 0) ssum[wid] = wsum;
    __syncthreads();
    float bs = (ssum[0] + ssum[1] + ssum[2] + ssum[3]) * 0.5f;

    if (h == 0) out[(size_t)gs * NN + j] = e / bs;
}

// ---------------------------------------------------------------------------
extern "C" void kernel_launch(void* const* d_in, const int* in_sizes, int n_in,
                              void* d_out, int out_size, void* d_ws, size_t ws_size,
                              hipStream_t stream) {
    (void)in_sizes; (void)n_in; (void)out_size; (void)d_ws; (void)ws_size;
    const float* x_s  = (const float*)d_in[0];
    const int*   ei_s = (const int*)  d_in[1];
    const float* x_t  = (const float*)d_in[3];
    const int*   ei_t = (const int*)  d_in[4];
    float* out = (float*)d_out;

    const int* dst_s = ei_s + NB * NN * DEG;   // second row of edge_index
    const int* dst_t = ei_t + NB * NN * DEG;

    hipLaunchKernelGGL(fused_kernel, dim3(NB * NN), dim3(256), 0, stream,
                       x_s, x_t, dst_s, dst_t, out);
}

// Round 6
// 26.181 us; speedup vs baseline: 1.1366x; 1.0521x over previous
//
#include <hip/hip_runtime.h>
#include <stdint.h>
#include <math.h>

#define NB 8
#define NN 128
#define NC 64
#define DEG 10
#define HP (DEG / 2)
#define NUM_STEPS 5

// ---------------------------------------------------------------------------
// Single fused kernel. Block = (b,i) with 256 threads, pair mapping
// j = tid>>1, h = tid&1 used for BOTH the sim phase and the Sinkhorn phase.
//
// sim phase: thread (j,h) holds HALF of x_t[j]'s channels (8 float4 = 32
// VGPR, not 64 -> keeps peak VGPR under the 128 occupancy cliff), computes
// 32-FMA partial dots vs <=11 x_s rows staged in LDS, combines with one
// shfl_xor(1) (commutative add -> identical on both lanes); h==0 writes
// srow/erow.
//
// sinkhorn: rank-factored S[p][q] == T[p][q]*a[p]*b[q] with T = exp(S_hat)
// (exp monotone + row-softmax normalizes => max-subtraction unnecessary;
// |sim| <~ 45 keeps all products finite). Thread h owns rows h*5..h*5+4.
// Column sums split p-wise across the pair, combined via shfl_xor(1);
// b-updates duplicated (identical inputs -> identical values). Row phase
// fully local. argmax_q S[p][q] == argmax_q T[p][q]*b[q] (a[p]>0 const/row).
// Neighbor extraction inline: bitmask + STATIC ctz walk (no runtime-indexed
// private arrays -> no scratch), ascending distinct == to_dense_adj->top_k.
// Masked entries stay EXACT zeros (predicated), matching the reference.
// ---------------------------------------------------------------------------
__global__ __launch_bounds__(256, 4) void fused_kernel(
    const float* __restrict__ xs, const float* __restrict__ xt,
    const int* __restrict__ dst_s, const int* __restrict__ dst_t,
    float* __restrict__ out)
{
    __shared__ float  srow[DEG + 1][NN];   // 0..9: neighbor sim rows; 10: self row
    __shared__ float  erow[DEG][NN];       // exp(sim) rows
    __shared__ float4 xsl[DEG + 1][NC / 4];
    __shared__ float  smax[4], ssum[4];

    const int bi  = blockIdx.x;
    const int b   = bi >> 7, i = bi & 127;
    const int tid = threadIdx.x;
    const int j   = tid >> 1;              // pair id / sim column 0..127
    const int h   = tid & 1;               // channel half / row half
    const int gs  = b * NN + i;
    const int gt  = b * NN + j;

    // ---- s-side neighbor mask (uniform across block -> scalar loads) ----
    unsigned long long slo = 0ull, shi = 0ull;
    #pragma unroll
    for (int k = 0; k < DEG; ++k) {
        int d = dst_s[gs * DEG + k] & (NN - 1);
        if (d < 64) slo |= 1ull << d; else shi |= 1ull << (d - 64);
    }
    const int dsi = __popcll(slo) + __popcll(shi);

    // ---- own half of x_t row j: 8 float4 = 32 VGPR, issued early ----
    const float4* xtr = (const float4*)(xt + (size_t)gt * NC) + h * (NC / 8);
    float4 xv[NC / 8];
    #pragma unroll
    for (int k = 0; k < NC / 8; ++k) xv[k] = xtr[k];

    // ---- stage x_s rows into LDS: threads 0..175, row = tid>>4, k = tid&15 ----
    if (tid < (DEG + 1) * 16) {
        int r = tid >> 4, k = tid & 15;
        int node = i;                       // r==10 -> self row
        if (r < DEG) {
            unsigned long long lo = slo, hi = shi; int sel = 0;
            #pragma unroll
            for (int q = 0; q < DEG; ++q) {   // static walk, scalar select
                int t;
                if (lo)      { t = __builtin_ctzll(lo);      lo &= lo - 1ull; }
                else if (hi) { t = 64 + __builtin_ctzll(hi); hi &= hi - 1ull; }
                else t = 0;
                if (q == r) sel = t;
            }
            node = sel;
        }
        if (r == DEG || r < dsi)
            xsl[r][k] = ((const float4*)(xs + (size_t)(b * NN + node) * NC))[k];
    }

    // ---- t-side neighbor list for pair j (before the sync, overlaps) ----
    unsigned long long tlo = 0ull, thi = 0ull;
    #pragma unroll
    for (int k = 0; k < DEG; ++k) {
        int d = dst_t[gt * DEG + k] & (NN - 1);
        if (d < 64) tlo |= 1ull << d; else thi |= 1ull << (d - 64);
    }
    const int dtj = __popcll(tlo) + __popcll(thi);
    int ntq[DEG];
    {
        unsigned long long lo = tlo, hi = thi;
        #pragma unroll
        for (int q = 0; q < DEG; ++q) {       // static-indexed writes
            int t;
            if (lo)      { t = __builtin_ctzll(lo);      lo &= lo - 1ull; }
            else if (hi) { t = 64 + __builtin_ctzll(hi); hi &= hi - 1ull; }
            else t = 0;
            ntq[q] = t;
        }
    }
    __syncthreads();

    // ---- sim dots: each thread does its channel-half vs all needed rows ----
    #pragma unroll
    for (int r = 0; r <= DEG; ++r) {
        bool need = (r == DEG) || (r < dsi);               // wave-uniform
        if (need) {
            float acc = 0.f;
            #pragma unroll
            for (int k = 0; k < NC / 8; ++k) {
                float4 a4 = xsl[r][h * (NC / 8) + k];      // 2-addr broadcast
                acc += a4.x * xv[k].x + a4.y * xv[k].y + a4.z * xv[k].z + a4.w * xv[k].w;
            }
            float full = acc + __shfl_xor(acc, 1);         // same on both lanes
            if (h == 0) {
                srow[r][j] = full;
                if (r < DEG) erow[r][j] = __expf(full);
            }
        }
    }
    __syncthreads();

    // ---- gather own half of T = exp(S_hat); a = (1/rowsum)/tau; b = valid?1:0
    float T[HP][DEG];
    float a[HP], bvv[DEG];
    #pragma unroll
    for (int q = 0; q < DEG; ++q) bvv[q] = (q < dtj) ? 1.0f : 0.0f;

    #pragma unroll
    for (int pp = 0; pp < HP; ++pp) {
        int p = h * HP + pp;
        bool pv = (p < dsi);
        float sum = 0.f;
        #pragma unroll
        for (int q = 0; q < DEG; ++q) {
            bool ok = pv && (q < dtj);
            float e = ok ? erow[p][ntq[q]] : 0.0f;
            T[pp][q] = e;
            sum += e;
        }
        a[pp] = pv ? __builtin_amdgcn_rcpf(sum) * 10.0f : 0.0f;
    }

    // ---- 5 Sinkhorn iterations on the scale vectors only ----
    #pragma unroll 1
    for (int it = 0; it < NUM_STEPS; ++it) {
        float part[DEG];
        #pragma unroll
        for (int q = 0; q < DEG; ++q) {
            float cc = T[0][q] * a[0];
            #pragma unroll
            for (int pp = 1; pp < HP; ++pp) cc = fmaf(T[pp][q], a[pp], cc);
            part[q] = cc;
        }
        #pragma unroll
        for (int q = 0; q < DEG; ++q) {
            float cc = part[q] + __shfl_xor(part[q], 1);   // same on both lanes
            float bq = bvv[q];
            bvv[q] = (q < dtj) ? bq * __builtin_amdgcn_rcpf(fmaf(bq, cc, 1e-8f)) : 0.0f;
        }
        #pragma unroll
        for (int pp = 0; pp < HP; ++pp) {
            float r = T[pp][0] * bvv[0];
            #pragma unroll
            for (int q = 1; q < DEG; ++q) r = fmaf(T[pp][q], bvv[q], r);
            float ap = a[pp];
            int p = h * HP + pp;
            a[pp] = (p < dsi) ? ap * __builtin_amdgcn_rcpf(fmaf(ap, r, 1e-8f)) : 0.0f;
        }
    }

    // ---- argmax per own row over T[pp][q]*b[q] (first max), cost gather ----
    float cpart = 0.f;
    #pragma unroll
    for (int pp = 0; pp < HP; ++pp) {
        int p = h * HP + pp;
        if (p < dsi) {
            float best = T[pp][0] * bvv[0];
            int   bc   = ntq[0];
            #pragma unroll
            for (int q = 1; q < DEG; ++q) {
                float vq = T[pp][q] * bvv[q];
                if (vq > best) { best = vq; bc = ntq[q]; }
            }
            cpart += srow[p][bc];
        }
    }
    float cost = cpart + __shfl_xor(cpart, 1);             // same on both lanes

    float M = (float)((dsi > dtj) ? dsi : dtj);
    float simv = srow[DEG][j];
    float v = simv + cost / (1.0f + M);

    // ---- block softmax over j: each pair's v appears twice -> sum * 0.5 ----
    float wm = v;
    #pragma unroll
    for (int off = 32; off; off >>= 1) wm = fmaxf(wm, __shfl_xor(wm, off));
    int wid = tid >> 6;
    if ((tid & 63) == 0) smax[wid] = wm;
    __syncthreads();
    float bm = fmaxf(fmaxf(smax[0], smax[1]), fmaxf(smax[2], smax[3]));
    float e = __expf(v - bm);
    float wsum = e;
    #pragma unroll
    for (int off = 32; off; off >>= 1) wsum += __shfl_xor(wsum, off);
    if ((tid & 63) == 0) ssum[wid] = wsum;
    __syncthreads();
    float bs = (ssum[0] + ssum[1] + ssum[2] + ssum[3]) * 0.5f;

    if (h == 0) out[(size_t)gs * NN + j] = e / bs;
}

// ---------------------------------------------------------------------------
extern "C" void kernel_launch(void* const* d_in, const int* in_sizes, int n_in,
                              void* d_out, int out_size, void* d_ws, size_t ws_size,
                              hipStream_t stream) {
    (void)in_sizes; (void)n_in; (void)out_size; (void)d_ws; (void)ws_size;
    const float* x_s  = (const float*)d_in[0];
    const int*   ei_s = (const int*)  d_in[1];
    const float* x_t  = (const float*)d_in[3];
    const int*   ei_t = (const int*)  d_in[4];
    float* out = (float*)d_out;

    const int* dst_s = ei_s + NB * NN * DEG;   // second row of edge_index
    const int* dst_t = ei_t + NB * NN * DEG;

    hipLaunchKernelGGL(fused_kernel, dim3(NB * NN), dim3(256), 0, stream,
                       x_s, x_t, dst_s, dst_t, out);
}

// Round 7
// 24.740 us; speedup vs baseline: 1.2028x; 1.0582x over previous
//
#include <hip/hip_runtime.h>
#include <stdint.h>
#include <math.h>

#define NB 8
#define NN 128
#define NC 64
#define DEG 10
#define HP (DEG / 2)
#define NUM_STEPS 5

// DPP pair swap: lanes 2k <-> 2k+1 (quad_perm [1,0,3,2] = 0xB1). Pure VALU —
// replaces ds_swizzle-based __shfl_xor(x,1) and its lgkmcnt stall on the
// Sinkhorn critical path. Callers are in convergent code (all lanes active).
__device__ __forceinline__ float pswap(float x) {
    return __int_as_float(__builtin_amdgcn_update_dpp(
        0, __float_as_int(x), 0xB1, 0xF, 0xF, false));
}

// ---------------------------------------------------------------------------
// Single fused kernel. Block = (b,i), 256 threads; pair mapping j = tid>>1,
// h = tid&1 for BOTH sim and Sinkhorn phases.
//
// sim: thread (j,h) holds half of x_t[j] (8 float4), 32-FMA partial dots vs
// <=11 x_s rows staged in LDS, combined with one DPP swap (commutative add ->
// identical on both lanes); h==0 writes srow/erow. Rows p>=dsi of erow are
// ZEROED and erow has a zero 129th column -> the T-gather needs no masking
// (masked entries are exact zeros by construction, matching the reference).
//
// sinkhorn: rank-factored S[p][q] == T[p][q]*a[p]*b[q], T = exp(S_hat)
// (exp monotone + row-softmax normalizes => max-subtraction unnecessary;
// |sim| <~ 45 keeps products finite). Thread h owns rows h*5..h*5+4; column
// sums split p-wise, combined via DPP; b-updates duplicated (identical
// inputs -> identical values); row phase local. b/a keep predication (a=inf
// or b->inf would poison row sums with 0*inf NaNs). argmax_q S == argmax_q
// T*b (a>0 const/row); q=0 is always valid (deg>=1) so NaN/zero slots can
// never win. Neighbor extraction: bitmask + STATIC ctz walk (no scratch).
// ---------------------------------------------------------------------------
__global__ __launch_bounds__(256, 4) void fused_kernel(
    const float* __restrict__ xs, const float* __restrict__ xt,
    const int* __restrict__ dst_s, const int* __restrict__ dst_t,
    float* __restrict__ out)
{
    __shared__ float  srow[DEG + 1][NN];    // 0..9 neighbor sim rows; 10 self
    __shared__ float  erow[DEG][NN + 1];    // exp rows; col NN is the zero col
    __shared__ float4 xsl[DEG + 1][NC / 4];
    __shared__ float  smax[4], ssum[4];

    const int bi  = blockIdx.x;
    const int b   = bi >> 7, i = bi & 127;
    const int tid = threadIdx.x;
    const int j   = tid >> 1;               // pair id / sim column
    const int h   = tid & 1;                // channel half / row half
    const int gs  = b * NN + i;
    const int gt  = b * NN + j;

    // ---- s-side neighbor mask (block-uniform -> scalar) ----
    unsigned long long slo = 0ull, shi = 0ull;
    #pragma unroll
    for (int k = 0; k < DEG; ++k) {
        int d = dst_s[gs * DEG + k] & (NN - 1);
        if (d < 64) slo |= 1ull << d; else shi |= 1ull << (d - 64);
    }
    const int dsi = __popcll(slo) + __popcll(shi);

    // ---- own half of x_t row j (8 float4 = 32 VGPR), issued early ----
    const float4* xtr = (const float4*)(xt + (size_t)gt * NC) + h * (NC / 8);
    float4 xv[NC / 8];
    #pragma unroll
    for (int k = 0; k < NC / 8; ++k) xv[k] = xtr[k];

    // ---- zero column of erow ----
    if (tid < DEG) erow[tid][NN] = 0.0f;

    // ---- stage x_s rows into LDS: threads 0..175, row = tid>>4, k = tid&15 ----
    if (tid < (DEG + 1) * 16) {
        int r = tid >> 4, k = tid & 15;
        int node = i;                        // r==10 -> self row
        if (r < DEG) {
            unsigned long long lo = slo, hi = shi; int sel = 0;
            #pragma unroll
            for (int q = 0; q < DEG; ++q) {  // static walk, scalar select
                int t;
                if (lo)      { t = __builtin_ctzll(lo);      lo &= lo - 1ull; }
                else if (hi) { t = 64 + __builtin_ctzll(hi); hi &= hi - 1ull; }
                else t = 0;
                if (q == r) sel = t;
            }
            node = sel;
        }
        if (r == DEG || r < dsi)
            xsl[r][k] = ((const float4*)(xs + (size_t)(b * NN + node) * NC))[k];
    }

    // ---- t-side neighbor list for pair j (overlaps before sync) ----
    unsigned long long tlo = 0ull, thi = 0ull;
    #pragma unroll
    for (int k = 0; k < DEG; ++k) {
        int d = dst_t[gt * DEG + k] & (NN - 1);
        if (d < 64) tlo |= 1ull << d; else thi |= 1ull << (d - 64);
    }
    const int dtj = __popcll(tlo) + __popcll(thi);
    int ntq[DEG];
    {
        unsigned long long lo = tlo, hi = thi;
        #pragma unroll
        for (int q = 0; q < DEG; ++q) {      // static-indexed writes
            int t;
            if (lo)      { t = __builtin_ctzll(lo);      lo &= lo - 1ull; }
            else if (hi) { t = 64 + __builtin_ctzll(hi); hi &= hi - 1ull; }
            else t = 0;
            ntq[q] = (q < dtj) ? t : NN;     // invalid -> zero column
        }
    }
    __syncthreads();

    // ---- sim dots; rows p>=dsi: zero-fill erow so gather needs no mask ----
    #pragma unroll
    for (int r = 0; r <= DEG; ++r) {
        if (r == DEG || r < dsi) {           // wave-uniform
            float acc = 0.f;
            #pragma unroll
            for (int k = 0; k < NC / 8; ++k) {
                float4 a4 = xsl[r][h * (NC / 8) + k];
                acc += a4.x * xv[k].x + a4.y * xv[k].y + a4.z * xv[k].z + a4.w * xv[k].w;
            }
            float full = acc + pswap(acc);   // identical on both lanes
            if (h == 0) {
                srow[r][j] = full;
                if (r < DEG) erow[r][j] = __expf(full);
            }
        } else {
            if (h == 0) erow[r][j] = 0.0f;
        }
    }
    __syncthreads();

    // ---- gather own half of T (unmasked: zeros by construction) ----
    float T[HP][DEG];
    float a[HP], bvv[DEG];
    #pragma unroll
    for (int q = 0; q < DEG; ++q) bvv[q] = (q < dtj) ? 1.0f : 0.0f;

    #pragma unroll
    for (int pp = 0; pp < HP; ++pp) {
        int p = h * HP + pp;
        float sum = 0.f;
        #pragma unroll
        for (int q = 0; q < DEG; ++q) {
            float e = erow[p][ntq[q]];
            T[pp][q] = e;
            sum += e;
        }
        a[pp] = (p < dsi) ? __builtin_amdgcn_rcpf(sum) * 10.0f : 0.0f;
    }

    // ---- 5 Sinkhorn iterations on the scale vectors only ----
    #pragma unroll 1
    for (int it = 0; it < NUM_STEPS; ++it) {
        float part[DEG];
        #pragma unroll
        for (int q = 0; q < DEG; ++q) {
            float cc = T[0][q] * a[0];
            #pragma unroll
            for (int pp = 1; pp < HP; ++pp) cc = fmaf(T[pp][q], a[pp], cc);
            part[q] = cc;
        }
        #pragma unroll
        for (int q = 0; q < DEG; ++q) {
            float cc = part[q] + pswap(part[q]);   // identical on both lanes
            float bq = bvv[q];
            bvv[q] = (q < dtj) ? bq * __builtin_amdgcn_rcpf(fmaf(bq, cc, 1e-8f)) : 0.0f;
        }
        #pragma unroll
        for (int pp = 0; pp < HP; ++pp) {
            float r = T[pp][0] * bvv[0];
            #pragma unroll
            for (int q = 1; q < DEG; ++q) r = fmaf(T[pp][q], bvv[q], r);
            float ap = a[pp];
            int p = h * HP + pp;
            a[pp] = (p < dsi) ? ap * __builtin_amdgcn_rcpf(fmaf(ap, r, 1e-8f)) : 0.0f;
        }
    }

    // ---- argmax per own row over T*b (first max), cost gather from LDS ----
    float cpart = 0.f;
    #pragma unroll
    for (int pp = 0; pp < HP; ++pp) {
        int p = h * HP + pp;
        if (p < dsi) {
            float best = T[pp][0] * bvv[0];   // q=0 always valid (deg>=1)
            int   bc   = ntq[0];
            #pragma unroll
            for (int q = 1; q < DEG; ++q) {
                float vq = T[pp][q] * bvv[q];
                if (vq > best) { best = vq; bc = ntq[q]; }
            }
            cpart += srow[p][bc];
        }
    }
    float cost = cpart + pswap(cpart);           // identical on both lanes

    float M = (float)((dsi > dtj) ? dsi : dtj);
    float simv = srow[DEG][j];
    float v = fmaf(cost, __builtin_amdgcn_rcpf(1.0f + M), simv);

    // ---- block softmax over j: each pair's v appears twice -> sum * 0.5 ----
    float wm = v;
    #pragma unroll
    for (int off = 32; off; off >>= 1) wm = fmaxf(wm, __shfl_xor(wm, off));
    int wid = tid >> 6;
    if ((tid & 63) == 0) smax[wid] = wm;
    __syncthreads();
    float bm = fmaxf(fmaxf(smax[0], smax[1]), fmaxf(smax[2], smax[3]));
    float e = __expf(v - bm);
    float wsum = e;
    #pragma unroll
    for (int off = 32; off; off >>= 1) wsum += __shfl_xor(wsum, off);
    if ((tid & 63) == 0) ssum[wid] = wsum;
    __syncthreads();
    float bs = (ssum[0] + ssum[1] + ssum[2] + ssum[3]) * 0.5f;

    if (h == 0) out[(size_t)gs * NN + j] = e * __builtin_amdgcn_rcpf(bs);
}

// ---------------------------------------------------------------------------
extern "C" void kernel_launch(void* const* d_in, const int* in_sizes, int n_in,
                              void* d_out, int out_size, void* d_ws, size_t ws_size,
                              hipStream_t stream) {
    (void)in_sizes; (void)n_in; (void)out_size; (void)d_ws; (void)ws_size;
    const float* x_s  = (const float*)d_in[0];
    const int*   ei_s = (const int*)  d_in[1];
    const float* x_t  = (const float*)d_in[3];
    const int*   ei_t = (const int*)  d_in[4];
    float* out = (float*)d_out;

    const int* dst_s = ei_s + NB * NN * DEG;   // second row of edge_index
    const int* dst_t = ei_t + NB * NN * DEG;

    hipLaunchKernelGGL(fused_kernel, dim3(NB * NN), dim3(256), 0, stream,
                       x_s, x_t, dst_s, dst_t, out);
}